// Round 3
// baseline (1091.134 us; speedup 1.0000x reference)
//
#include <hip/hip_runtime.h>
#include <cmath>

constexpr int BN = 4, CN = 128, HN = 256, WN = 256;
constexpr int NPLANE = BN * CN;          // 512
constexpr int PLANE  = HN * WN;          // 65536

// workspace layout (float offsets); end = 39,146,496 floats = 157 MB
constexpr long long OF_THR = 0;                                  // 1024
constexpr long long OF_R1  = 1024;                               // 2*512*128*128
constexpr long long OF_D1  = OF_R1 + 2LL * NPLANE * 128 * 128;
constexpr long long OF_D2  = OF_D1 + 2LL * NPLANE * 128 * 128;
constexpr long long OF_D3  = OF_D2 + 2LL * NPLANE * 64 * 64;
constexpr long long OF_D4  = OF_D3 + 2LL * NPLANE * 32 * 32;
constexpr long long OF_D5  = OF_D4 + 2LL * NPLANE * 16 * 16;
constexpr long long OF_D6  = OF_D5 + 2LL * NPLANE * 8 * 8;
constexpr long long OF_D7  = OF_D6 + 2LL * NPLANE * 4 * 4;
// stats partials are parked in the (not yet written) D1 region.

static __device__ __forceinline__ float sigm100(float a, float thr) {
    return 1.f / (1.f + __expf(-100.f * (a - thr))) + 1e-6f;
}

// --------------------------------------------------------------- statsA ----
// partial sums per (plane, 16-row strip) -> float4 partials in D1 region
__global__ __launch_bounds__(256) void statsA_kernel(const float* __restrict__ x,
                                                     float* __restrict__ ws) {
    const int strip = blockIdx.x;   // 0..15
    const int p = blockIdx.y;       // 0..511
    const int tid = threadIdx.x;
    const float* xp = x + (long long)p * PLANE + strip * 4096;
    float sp = 0, spp = 0, sn = 0, snn = 0;
    for (int i = tid; i < 4096; i += 256) {
        float v = xp[i];
        float a = fmaxf(v, 0.f), b = fmaxf(-v, 0.f);
        sp += a; spp += a * a;
        sn += b; snn += b * b;
    }
    __shared__ float red[256];
    float vals[4] = {sp, spp, sn, snn};
    float* dst = ws + OF_D1 + ((long long)p * 16 + strip) * 4;
    for (int q = 0; q < 4; q++) {
        red[tid] = vals[q];
        __syncthreads();
        for (int s = 128; s > 0; s >>= 1) {
            if (tid < s) red[tid] += red[tid + s];
            __syncthreads();
        }
        if (tid == 0) dst[q] = red[0];
        __syncthreads();
    }
}

// --------------------------------------------------------------- statsB ----
__global__ __launch_bounds__(256) void statsB_kernel(float* __restrict__ ws) {
    int p = blockIdx.x * 256 + threadIdx.x;   // grid 2 x 256 -> 512 planes
    if (p >= 512) return;
    double sp = 0, spp = 0, sn = 0, snn = 0;
    for (int s = 0; s < 16; s++) {
        const float* src = ws + OF_D1 + ((long long)p * 16 + s) * 4;
        sp += src[0]; spp += src[1]; sn += src[2]; snn += src[3];
    }
    double N = (double)PLANE;
    double meanP = sp / N, meanN = sn / N;
    double varP = (spp - sp * sp / N) / (N - 1.0);
    double varN = (snn - sn * sn / N) / (N - 1.0);
    varP = varP > 0 ? varP : 0;
    varN = varN > 0 ? varN : 0;
    ws[OF_THR + p]       = (float)(meanP + 2.0 * sqrt(varP));
    ws[OF_THR + 512 + p] = (float)(meanN + 2.0 * sqrt(varN));
}

// -------------------------------------------------- field -> r1 only ----
// Combined-sign field c = v * sigm(|v|, thr_sign): fieldP = max(c,0),
// fieldN = max(-c,0). Clamp-duplicate halo (max/min over clamped multiset
// == over valid set, replacing the -inf pad). One block = one 64x64 tile;
// the 256->128 align-corners resize partitions exactly on 64-px tiles.
__global__ __launch_bounds__(256, 3) void field_kernel(const float* __restrict__ x,
                                                       float* __restrict__ ws) {
    const int tile = blockIdx.x;           // 0..15  (ty*4+tx)
    const int p = blockIdx.y;              // 0..511
    const int ty = tile >> 2, tx = tile & 3;
    const int y0 = ty * 64, x0 = tx * 64;
    const int tid = threadIdx.x;

    __shared__ float cf[66 * 66];
    __shared__ float plP[64 * 64];
    __shared__ float plN[64 * 64];

    const float thrP = ws[OF_THR + p];
    const float thrN = ws[OF_THR + 512 + p];
    const float* xp = x + (long long)p * PLANE;

    for (int i = tid; i < 66 * 66; i += 256) {
        int ly = i / 66, lx = i - ly * 66;
        int gy = min(max(y0 - 1 + ly, 0), 255);
        int gx = min(max(x0 - 1 + lx, 0), 255);
        float v = xp[gy * 256 + gx];
        float thr = v > 0.f ? thrP : thrN;
        cf[i] = v * sigm100(fabsf(v), thr);
    }
    __syncthreads();

    const float g1 = 0.99f;
    for (int i = tid; i < 64 * 64; i += 256) {
        int oy = i >> 6, ox = i & 63;
        const float* r0 = cf + oy * 66 + ox;
        const float* r1r = r0 + 66;
        const float* r2 = r1r + 66;
        float cmax = fmaxf(fmaxf(r0[0], r0[1]), r0[2]);
        float cmin = fminf(fminf(r0[0], r0[1]), r0[2]);
        cmax = fmaxf(cmax, fmaxf(fmaxf(r1r[0], r1r[1]), r1r[2]));
        cmin = fminf(cmin, fminf(fminf(r1r[0], r1r[1]), r1r[2]));
        cmax = fmaxf(cmax, fmaxf(fmaxf(r2[0], r2[1]), r2[2]));
        cmin = fminf(cmin, fminf(fminf(r2[0], r2[1]), r2[2]));
        plP[i] = fmaxf(cmax, 0.f) * g1;
        plN[i] = fmaxf(-cmin, 0.f) * g1;
    }
    __syncthreads();

    const float S = (float)(255.0 / 127.0);
    for (int i = tid; i < 32 * 32; i += 256) {
        int ry = i >> 5, rx = i & 31;
        int jy = ty * 32 + ry, jx = tx * 32 + rx;
        float uy = jy * S, ux = jx * S;
        int iy0 = (int)floorf(uy), ix0 = (int)floorf(ux);
        int iy1 = min(iy0 + 1, 255), ix1 = min(ix0 + 1, 255);
        float fy = uy - iy0, fx = ux - ix0;
        int ly0 = min(max(iy0 - y0, 0), 63), ly1 = min(max(iy1 - y0, 0), 63);
        int lx0 = min(max(ix0 - x0, 0), 63), lx1 = min(max(ix1 - x0, 0), 63);
        float aP = plP[ly0 * 64 + lx0], bP = plP[ly0 * 64 + lx1];
        float cP = plP[ly1 * 64 + lx0], dP = plP[ly1 * 64 + lx1];
        float vP = (aP * (1.f - fy) + cP * fy) * (1.f - fx) + (bP * (1.f - fy) + dP * fy) * fx;
        float aN = plN[ly0 * 64 + lx0], bN = plN[ly0 * 64 + lx1];
        float cN = plN[ly1 * 64 + lx0], dN = plN[ly1 * 64 + lx1];
        float vN = (aN * (1.f - fy) + cN * fy) * (1.f - fx) + (bN * (1.f - fy) + dN * fy) * fx;
        ws[OF_R1 + (long long)p * 16384 + jy * 128 + jx] = vP;
        ws[OF_R1 + (long long)(512 + p) * 16384 + jy * 128 + jx] = vN;
    }
}

// ---------------------------------------------------------------- pool1 ----
__global__ __launch_bounds__(256) void pool1_kernel(float* __restrict__ ws, float gamma2) {
    long long gid = (long long)blockIdx.x * 256 + threadIdx.x;
    int ps = (int)(gid >> 14);
    int rem = (int)(gid & 16383);
    int oy = rem >> 7, ox = rem & 127;
    const float* src = ws + OF_R1 + (long long)ps * 16384;
    float m = -INFINITY;
    for (int dy = -1; dy <= 1; dy++) {
        int yy = oy + dy;
        if (yy < 0 || yy > 127) continue;
        for (int dx = -1; dx <= 1; dx++) {
            int xx = ox + dx;
            if (xx < 0 || xx > 127) continue;
            m = fmaxf(m, src[yy * 128 + xx]);
        }
    }
    ws[OF_D1 + (long long)ps * 16384 + rem] = m * gamma2;
}

// ------------------------------------------------- pyramid step (k>=2) ----
__global__ __launch_bounds__(256) void pstep_kernel(float* __restrict__ ws,
                                                    long long srcOff, long long dstOff,
                                                    int m, int n, int logn,
                                                    float scale, float gamma) {
    int gid = blockIdx.x * 256 + threadIdx.x;
    int ps = gid >> (2 * logn);
    int rem = gid & ((1 << (2 * logn)) - 1);
    int oy = rem >> logn, ox = rem & ((1 << logn) - 1);
    const float* src = ws + srcOff + (long long)ps * m * m;
    float best = -INFINITY;
    for (int dy = -1; dy <= 1; dy++) {
        int yy = oy + dy;
        if (yy < 0 || yy >= n) continue;
        float uy = yy * scale;
        int iy0 = (int)floorf(uy);
        if (iy0 > m - 1) iy0 = m - 1;
        int iy1 = min(iy0 + 1, m - 1);
        float fy = uy - iy0;
        for (int dx = -1; dx <= 1; dx++) {
            int xx = ox + dx;
            if (xx < 0 || xx >= n) continue;
            float ux = xx * scale;
            int ix0 = (int)floorf(ux);
            if (ix0 > m - 1) ix0 = m - 1;
            int ix1 = min(ix0 + 1, m - 1);
            float fx = ux - ix0;
            float a = src[iy0 * m + ix0], b = src[iy0 * m + ix1];
            float c = src[iy1 * m + ix0], d = src[iy1 * m + ix1];
            float v = (a * (1.f - fy) + c * fy) * (1.f - fx) + (b * (1.f - fy) + d * fy) * fx;
            best = fmaxf(best, v);
        }
    }
    ws[dstOff + (long long)ps * n * n + rem] = best * gamma;
}

// ------------------------------------------------------------- radiance ----
// One block = 256x16 row-tile of one plane, both signs. Combined-sign field
// in LDS (18x258). Pyramid footprints read straight from GLOBAL (L2/L3-
// resident) into per-level NAMED SCALAR register caches.
// ROUND-2 LESSON: per-level state held in small arrays (xl0P[8], cy[8], ...)
// was never SROA-promoted -> lived in scratch -> +740 MB of HBM traffic at
// VGPR_Count=40. Fix per rule #20: hand-scalarize via per-level macros with
// literal N; every local is a named scalar, pointer bases are plane-uniform
// (fold to SGPR). ~75 VGPR live < 84 cap from (256,6): 6 blocks/CU.
// Arithmetic is bit-identical to the staged version.

#define LVL_INIT(K, N)                                                        \
    const float sc##K = (float)((N) - 1) / 255.f;                             \
    const float* bP##K = ws + OF_D##K + (long long)p * (N) * (N);             \
    const float* bN##K = bP##K + 512LL * (N) * (N);                           \
    int j0##K, j1##K; float fx##K;                                            \
    {   float ux = tid * sc##K;                                               \
        int a = (int)ux; if (a > (N) - 1) a = (N) - 1;                        \
        j0##K = a; j1##K = min(a + 1, (N) - 1);                               \
        fx##K = ux - (float)a; }                                              \
    int cy##K = (int)floorf(Y0 * sc##K);                                      \
    float xl0P##K, xl1P##K, xl0N##K, xl1N##K;                                 \
    {   int i0 = cy##K, i1 = min(i0 + 1, (N) - 1);                            \
        float a = bP##K[i0 * (N) + j0##K], e = bP##K[i0 * (N) + j1##K];       \
        float c = bP##K[i1 * (N) + j0##K], d = bP##K[i1 * (N) + j1##K];       \
        xl0P##K = a + fx##K * (e - a);                                        \
        xl1P##K = c + fx##K * (d - c);                                        \
        float an = bN##K[i0 * (N) + j0##K], en = bN##K[i0 * (N) + j1##K];     \
        float cn = bN##K[i1 * (N) + j0##K], dn = bN##K[i1 * (N) + j1##K];     \
        xl0N##K = an + fx##K * (en - an);                                     \
        xl1N##K = cn + fx##K * (dn - cn); }

#define LVL_STEP(K, N)                                                        \
    {   float uy = row * sc##K;                                               \
        int i0 = (int)uy;                                                     \
        if (i0 != cy##K) {            /* wave-uniform advance (by 1) */       \
            cy##K = i0;                                                       \
            xl0P##K = xl1P##K; xl0N##K = xl1N##K;                             \
            int i1 = min(i0 + 1, (N) - 1);                                    \
            const float* rP = bP##K + i1 * (N);                               \
            const float* rN = bN##K + i1 * (N);                               \
            float a = rP[j0##K], e = rP[j1##K];                               \
            xl1P##K = a + fx##K * (e - a);                                    \
            float an = rN[j0##K], en = rN[j1##K];                             \
            xl1N##K = an + fx##K * (en - an);                                 \
        }                                                                     \
        float fy = uy - (float)i0;                                            \
        mP = fmaxf(mP, xl0P##K + fy * (xl1P##K - xl0P##K));                   \
        mN = fmaxf(mN, xl0N##K + fy * (xl1N##K - xl0N##K)); }

__global__ __launch_bounds__(256, 6) void radiance_kernel(const float* __restrict__ x,
                                                          const float* __restrict__ ws,
                                                          float* __restrict__ rad) {
    const int tY = blockIdx.x;     // 0..15
    const int p = blockIdx.y;      // 0..511
    const int Y0 = tY * 16;
    const int tid = threadIdx.x;   // = column

    __shared__ float cf[18 * 258];   // combined field rows Y0-1..Y0+16 (clamped)

    const float thrP = ws[OF_THR + p];
    const float thrN = ws[OF_THR + 512 + p];
    const float* xp = x + (long long)p * PLANE;

    // stage combined field; cols duplicated at 0 and 257 (clamp trick)
    for (int r = 0; r < 18; r++) {
        int gy = min(max(Y0 - 1 + r, 0), 255);
        float v = xp[gy * 256 + tid];
        float thr = v > 0.f ? thrP : thrN;
        float c = v * sigm100(fabsf(v), thr);
        cf[r * 258 + tid + 1] = c;
        if (tid == 0) cf[r * 258] = c;
        if (tid == 255) cf[r * 258 + 257] = c;
    }

    // per-level scalar state + initial two x-lerped footprint rows (global)
    LVL_INIT(1, 128)
    LVL_INIT(2, 64)
    LVL_INIT(3, 32)
    LVL_INIT(4, 16)
    LVL_INIT(5, 8)
    LVL_INIT(6, 4)
    LVL_INIT(7, 2)

    __syncthreads();   // cf ready (global loads above overlap the barrier)

    // level-0 streaming rings (rows lr-1, lr, lr+1)
    float hx0, hx1, hx2, hn0, hn1, hn2, cc1, cc2;
    {
        int b0 = 0 * 258 + tid;
        float a = cf[b0], b = cf[b0 + 1], c = cf[b0 + 2];
        hx0 = fmaxf(fmaxf(a, b), c); hn0 = fminf(fminf(a, b), c);
        int b1 = 1 * 258 + tid;
        float d = cf[b1], e = cf[b1 + 1], f = cf[b1 + 2];
        hx1 = fmaxf(fmaxf(d, e), f); hn1 = fminf(fminf(d, e), f);
        cc1 = e;
    }

    float* radp = rad + (long long)p * PLANE + (long long)Y0 * 256 + tid;

    for (int q = 0; q < 16; q++) {
        // next field row (lr+1 = q+2)
        int bn = (q + 2) * 258 + tid;
        float a = cf[bn], b = cf[bn + 1], c = cf[bn + 2];
        hx2 = fmaxf(fmaxf(a, b), c); hn2 = fminf(fminf(a, b), c);
        cc2 = b;

        float poolmax = fmaxf(fmaxf(hx0, hx1), hx2);
        float poolmin = fminf(fminf(hn0, hn1), hn2);
        float mP = fmaxf(fmaxf(cc1, 0.f), 0.99f * fmaxf(poolmax, 0.f));
        float mN = fmaxf(fmaxf(-cc1, 0.f), 0.99f * fmaxf(-poolmin, 0.f));

        int row = Y0 + q;
        LVL_STEP(1, 128)
        LVL_STEP(2, 64)
        LVL_STEP(3, 32)
        LVL_STEP(4, 16)
        LVL_STEP(5, 8)
        LVL_STEP(6, 4)
        LVL_STEP(7, 2)

        radp[q * 256] = mP - mN;

        hx0 = hx1; hx1 = hx2;
        hn0 = hn1; hn1 = hn2;
        cc1 = cc2;
    }
}

// ------------------------------------------------------------------ mlp ----
// io holds rad on entry, final output on exit (per-thread read set == write
// set; all reads precede all writes within a thread).
__global__ __launch_bounds__(256) void mlp_kernel(const float* __restrict__ x,
                                                  const float* __restrict__ w1,
                                                  const float* __restrict__ b1,
                                                  const float* __restrict__ w2,
                                                  const float* __restrict__ b2,
                                                  float* io) {
    const int y = blockIdx.x;   // 0..255
    const int b = blockIdx.y;   // 0..3
    const int col = threadIdx.x;

    float h[16];
#pragma unroll
    for (int o = 0; o < 16; o++) h[o] = b1[o];
    for (int c = 0; c < 128; c++) {
        float r = io[(long long)(b * 128 + c) * PLANE + y * 256 + col];
#pragma unroll
        for (int o = 0; o < 16; o++) h[o] += w1[o * 128 + c] * r;
    }
#pragma unroll
    for (int o = 0; o < 16; o++) h[o] = fmaxf(h[o], 0.f);
    for (int c = 0; c < 128; c++) {
        float z = b2[c];
#pragma unroll
        for (int o = 0; o < 16; o++) z += w2[c * 16 + o] * h[o];
        float mod = 1.f / (1.f + __expf(-z));
        long long idx = (long long)(b * 128 + c) * PLANE + y * 256 + col;
        io[idx] = x[idx] * mod;
    }
}

// -------------------------------------------------------------- launcher ----
extern "C" void kernel_launch(void* const* d_in, const int* in_sizes, int n_in,
                              void* d_out, int out_size, void* d_ws, size_t ws_size,
                              hipStream_t stream) {
    (void)in_sizes; (void)n_in; (void)out_size; (void)ws_size;
    const float* x  = (const float*)d_in[0];
    const float* w1 = (const float*)d_in[1];
    const float* b1 = (const float*)d_in[2];
    const float* w2 = (const float*)d_in[3];
    const float* b2 = (const float*)d_in[4];
    float* out = (float*)d_out;
    float* ws = (float*)d_ws;

    statsA_kernel<<<dim3(16, 512), 256, 0, stream>>>(x, ws);
    statsB_kernel<<<2, 256, 0, stream>>>(ws);
    field_kernel<<<dim3(16, 512), 256, 0, stream>>>(x, ws);
    pool1_kernel<<<(1024 * 16384) / 256, 256, 0, stream>>>(ws, (float)std::pow(0.99, 2.0));

    const long long dsts[8] = {0, OF_D1, OF_D2, OF_D3, OF_D4, OF_D5, OF_D6, OF_D7};
    for (int k = 2; k <= 7; k++) {
        int m = 256 >> (k - 1), n = 256 >> k;
        int logn = 8 - k;
        float scale = (float)((double)(m - 1) / (double)(n - 1));
        float gamma = (float)std::pow(0.99, (double)(1 << k));
        int total = 1024 * n * n;
        pstep_kernel<<<total / 256, 256, 0, stream>>>(ws, dsts[k - 1], dsts[k],
                                                      m, n, logn, scale, gamma);
    }
    radiance_kernel<<<dim3(16, 512), 256, 0, stream>>>(x, ws, out);
    mlp_kernel<<<dim3(256, 4), 256, 0, stream>>>(x, w1, b1, w2, b2, out);
}

// Round 4
// 943.974 us; speedup vs baseline: 1.1559x; 1.1559x over previous
//
#include <hip/hip_runtime.h>
#include <cmath>

constexpr int BN = 4, CN = 128, HN = 256, WN = 256;
constexpr int NPLANE = BN * CN;          // 512
constexpr int PLANE  = HN * WN;          // 65536

// workspace layout (float offsets); end = 39,146,496 floats = 157 MB
constexpr long long OF_THR = 0;                                  // 1024
constexpr long long OF_R1  = 1024;                               // 2*512*128*128
constexpr long long OF_D1  = OF_R1 + 2LL * NPLANE * 128 * 128;
constexpr long long OF_D2  = OF_D1 + 2LL * NPLANE * 128 * 128;
constexpr long long OF_D3  = OF_D2 + 2LL * NPLANE * 64 * 64;
constexpr long long OF_D4  = OF_D3 + 2LL * NPLANE * 32 * 32;
constexpr long long OF_D5  = OF_D4 + 2LL * NPLANE * 16 * 16;
constexpr long long OF_D6  = OF_D5 + 2LL * NPLANE * 8 * 8;
constexpr long long OF_D7  = OF_D6 + 2LL * NPLANE * 4 * 4;
// stats partials are parked in the (not yet written) D1 region.

static __device__ __forceinline__ float sigm100(float a, float thr) {
    return 1.f / (1.f + __expf(-100.f * (a - thr))) + 1e-6f;
}

// --------------------------------------------------------------- statsA ----
// partial sums per (plane, 16-row strip) -> float4 partials in D1 region
__global__ __launch_bounds__(256) void statsA_kernel(const float* __restrict__ x,
                                                     float* __restrict__ ws) {
    const int strip = blockIdx.x;   // 0..15
    const int p = blockIdx.y;       // 0..511
    const int tid = threadIdx.x;
    const float* xp = x + (long long)p * PLANE + strip * 4096;
    float sp = 0, spp = 0, sn = 0, snn = 0;
    for (int i = tid; i < 4096; i += 256) {
        float v = xp[i];
        float a = fmaxf(v, 0.f), b = fmaxf(-v, 0.f);
        sp += a; spp += a * a;
        sn += b; snn += b * b;
    }
    __shared__ float red[256];
    float vals[4] = {sp, spp, sn, snn};
    float* dst = ws + OF_D1 + ((long long)p * 16 + strip) * 4;
    for (int q = 0; q < 4; q++) {
        red[tid] = vals[q];
        __syncthreads();
        for (int s = 128; s > 0; s >>= 1) {
            if (tid < s) red[tid] += red[tid + s];
            __syncthreads();
        }
        if (tid == 0) dst[q] = red[0];
        __syncthreads();
    }
}

// --------------------------------------------------------------- statsB ----
__global__ __launch_bounds__(256) void statsB_kernel(float* __restrict__ ws) {
    int p = blockIdx.x * 256 + threadIdx.x;   // grid 2 x 256 -> 512 planes
    if (p >= 512) return;
    double sp = 0, spp = 0, sn = 0, snn = 0;
    for (int s = 0; s < 16; s++) {
        const float* src = ws + OF_D1 + ((long long)p * 16 + s) * 4;
        sp += src[0]; spp += src[1]; sn += src[2]; snn += src[3];
    }
    double N = (double)PLANE;
    double meanP = sp / N, meanN = sn / N;
    double varP = (spp - sp * sp / N) / (N - 1.0);
    double varN = (snn - sn * sn / N) / (N - 1.0);
    varP = varP > 0 ? varP : 0;
    varN = varN > 0 ? varN : 0;
    ws[OF_THR + p]       = (float)(meanP + 2.0 * sqrt(varP));
    ws[OF_THR + 512 + p] = (float)(meanN + 2.0 * sqrt(varN));
}

// -------------------------------------------------- field -> r1 only ----
// Combined-sign field c = v * sigm(|v|, thr_sign). One block = one 64x64
// tile. ROUND-4: the plP/plN 32 KB LDS staging is gone — the 4 pooled
// values each resize output needs are computed directly from cf with the
// SAME 9-point windows / clamps / lerp as before (bit-identical). LDS
// drops 50 KB -> 17.4 KB => 8 blocks/CU instead of 3.
#define POOL9(LY, LX, MX, MN)                                                 \
    {   const float* q_ = cf + (LY) * 66 + (LX);                              \
        float t0 = q_[0],   t1 = q_[1],   t2 = q_[2];                         \
        float u0 = q_[66],  u1 = q_[67],  u2 = q_[68];                        \
        float w0 = q_[132], w1 = q_[133], w2 = q_[134];                       \
        MX = fmaxf(fmaxf(fmaxf(t0, t1), t2),                                  \
             fmaxf(fmaxf(fmaxf(u0, u1), u2),                                  \
                   fmaxf(fmaxf(w0, w1), w2)));                                \
        MN = fminf(fminf(fminf(t0, t1), t2),                                  \
             fminf(fminf(fminf(u0, u1), u2),                                  \
                   fminf(fminf(w0, w1), w2))); }

__global__ __launch_bounds__(256, 8) void field_kernel(const float* __restrict__ x,
                                                       float* __restrict__ ws) {
    const int tile = blockIdx.x;           // 0..15  (ty*4+tx)
    const int p = blockIdx.y;              // 0..511
    const int ty = tile >> 2, tx = tile & 3;
    const int y0 = ty * 64, x0 = tx * 64;
    const int tid = threadIdx.x;

    __shared__ float cf[66 * 66];

    const float thrP = ws[OF_THR + p];
    const float thrN = ws[OF_THR + 512 + p];
    const float* xp = x + (long long)p * PLANE;

    for (int i = tid; i < 66 * 66; i += 256) {
        int ly = i / 66, lx = i - ly * 66;
        int gy = min(max(y0 - 1 + ly, 0), 255);
        int gx = min(max(x0 - 1 + lx, 0), 255);
        float v = xp[gy * 256 + gx];
        float thr = v > 0.f ? thrP : thrN;
        cf[i] = v * sigm100(fabsf(v), thr);
    }
    __syncthreads();

    const float g1 = 0.99f;
    const float S = (float)(255.0 / 127.0);
    for (int i = tid; i < 32 * 32; i += 256) {
        int ry = i >> 5, rx = i & 31;
        int jy = ty * 32 + ry, jx = tx * 32 + rx;
        float uy = jy * S, ux = jx * S;
        int iy0 = (int)floorf(uy), ix0 = (int)floorf(ux);
        int iy1 = min(iy0 + 1, 255), ix1 = min(ix0 + 1, 255);
        float fy = uy - iy0, fx = ux - ix0;
        int ly0 = min(max(iy0 - y0, 0), 63), ly1 = min(max(iy1 - y0, 0), 63);
        int lx0 = min(max(ix0 - x0, 0), 63), lx1 = min(max(ix1 - x0, 0), 63);

        float amx, amn, bmx, bmn, cmx, cmn, dmx, dmn;
        POOL9(ly0, lx0, amx, amn)
        POOL9(ly0, lx1, bmx, bmn)
        POOL9(ly1, lx0, cmx, cmn)
        POOL9(ly1, lx1, dmx, dmn)

        float aP = fmaxf(amx, 0.f) * g1, bP = fmaxf(bmx, 0.f) * g1;
        float cP = fmaxf(cmx, 0.f) * g1, dP = fmaxf(dmx, 0.f) * g1;
        float vP = (aP * (1.f - fy) + cP * fy) * (1.f - fx) + (bP * (1.f - fy) + dP * fy) * fx;
        float aN = fmaxf(-amn, 0.f) * g1, bN = fmaxf(-bmn, 0.f) * g1;
        float cN = fmaxf(-cmn, 0.f) * g1, dN = fmaxf(-dmn, 0.f) * g1;
        float vN = (aN * (1.f - fy) + cN * fy) * (1.f - fx) + (bN * (1.f - fy) + dN * fy) * fx;
        ws[OF_R1 + (long long)p * 16384 + jy * 128 + jx] = vP;
        ws[OF_R1 + (long long)(512 + p) * 16384 + jy * 128 + jx] = vN;
    }
}

// -------------------------------------------------------------- pyramid ----
// ROUND-4: pool1 + 6 pstep launches fused into one kernel. One block per
// sign-plane (1024 blocks). D1 computed from global R1 (pool3 * 0.99^2),
// written to global AND kept in LDS; levels 2..7 ping-pong A<->B in LDS,
// each also written to global for radiance. Math identical to the old
// pool1/pstep kernels; gammas by double repeated squaring (== std::pow to
// the ulp for these arguments).
__global__ __launch_bounds__(256, 2) void pyramid_kernel(float* __restrict__ ws) {
    const int ps = blockIdx.x;        // 0..1023 (sign*512 + plane)
    const int tid = threadIdx.x;
    __shared__ float A[16384];        // 64 KB
    __shared__ float B[4096];         // 16 KB

    // ---- level 1: 3x3 max pool on R1, * 0.99^2 ----
    const float* src = ws + OF_R1 + (long long)ps * 16384;
    float* d1 = ws + OF_D1 + (long long)ps * 16384;
    double gd = 0.99 * 0.99;
    {
        float g2 = (float)gd;
        for (int i = tid; i < 16384; i += 256) {
            int oy = i >> 7, ox = i & 127;
            float m = -INFINITY;
            for (int dy = -1; dy <= 1; dy++) {
                int yy = oy + dy;
                if (yy < 0 || yy > 127) continue;
                for (int dx = -1; dx <= 1; dx++) {
                    int xx = ox + dx;
                    if (xx < 0 || xx > 127) continue;
                    m = fmaxf(m, src[yy * 128 + xx]);
                }
            }
            float v = m * g2;
            d1[i] = v; A[i] = v;
        }
    }
    __syncthreads();

    // ---- levels 2..7: bilinear-downscale + pool3, ping-pong in LDS ----
    const long long OFD[8] = {0, OF_D1, OF_D2, OF_D3, OF_D4, OF_D5, OF_D6, OF_D7};
    float* curL = A;
    float* nxtL = B;
#pragma unroll
    for (int k = 2; k <= 7; k++) {
        const int m = 256 >> (k - 1), n = 256 >> k;
        const int logn = 8 - k;
        gd = gd * gd;                                   // 0.99^(2^k)
        const float gamma = (float)gd;
        const float scale = (float)((double)(m - 1) / (double)(n - 1));
        float* dst = ws + OFD[k] + (long long)ps * n * n;
        for (int i = tid; i < n * n; i += 256) {
            int oy = i >> logn, ox = i & (n - 1);
            float best = -INFINITY;
            for (int dy = -1; dy <= 1; dy++) {
                int yy = oy + dy;
                if (yy < 0 || yy >= n) continue;
                float uy = yy * scale;
                int iy0 = (int)floorf(uy);
                if (iy0 > m - 1) iy0 = m - 1;
                int iy1 = min(iy0 + 1, m - 1);
                float fy = uy - iy0;
                for (int dx = -1; dx <= 1; dx++) {
                    int xx = ox + dx;
                    if (xx < 0 || xx >= n) continue;
                    float ux = xx * scale;
                    int ix0 = (int)floorf(ux);
                    if (ix0 > m - 1) ix0 = m - 1;
                    int ix1 = min(ix0 + 1, m - 1);
                    float fx = ux - ix0;
                    float a = curL[iy0 * m + ix0], b = curL[iy0 * m + ix1];
                    float c = curL[iy1 * m + ix0], d = curL[iy1 * m + ix1];
                    float v = (a * (1.f - fy) + c * fy) * (1.f - fx) + (b * (1.f - fy) + d * fy) * fx;
                    best = fmaxf(best, v);
                }
            }
            float o = best * gamma;
            dst[i] = o; nxtL[i] = o;
        }
        __syncthreads();
        float* t = curL; curL = nxtL; nxtL = t;
    }
}

// ------------------------------------------------------------- radiance ----
// ROUND-4: back to the proven round-0 LDS-staged structure (rounds 1-3's
// global-gather variants all generated scratch traffic). LDS diet instead:
// levels 2..7 staged as before (600 floats/sign), but level-1 (10 of the
// 15.4 KB fpb) becomes a 2-row LDS ring refreshed cooperatively from global
// on the (block-uniform) y-advance, barrier-protected. LDS 34.3 -> 25.4 KB
// => 6 blocks/CU instead of 4. All footprint data still flows through LDS;
// per-thread state shape identical to round 0 (52 VGPR, no scratch there).
__global__ __launch_bounds__(256, 6) void radiance_kernel(const float* __restrict__ x,
                                                          const float* __restrict__ ws,
                                                          float* __restrict__ rad) {
    const int tY = blockIdx.x;     // 0..15
    const int p = blockIdx.y;      // 0..511
    const int Y0 = tY * 16;
    const int tid = threadIdx.x;   // = column

    __shared__ float cf[18 * 258];   // combined field rows Y0-1..Y0+16 (18576 B)
    __shared__ float fpb[2 * 600];   // pyramid footprints k=2..7, both signs (4800 B)
    __shared__ float fp1P[2 * 128];  // level-1 ring, sign P (1024 B)
    __shared__ float fp1N[2 * 128];  // level-1 ring, sign N (1024 B)

    const float thrP = ws[OF_THR + p];
    const float thrN = ws[OF_THR + 512 + p];
    const float* xp = x + (long long)p * PLANE;

    // stage combined field; cols duplicated at 0 and 257 (clamp trick)
    for (int r = 0; r < 18; r++) {
        int gy = min(max(Y0 - 1 + r, 0), 255);
        float v = xp[gy * 256 + tid];
        float thr = v > 0.f ? thrP : thrN;
        float c = v * sigm100(fabsf(v), thr);
        cf[r * 258 + tid + 1] = c;
        if (tid == 0) cf[r * 258] = c;
        if (tid == 255) cf[r * 258 + 257] = c;
    }

    // footprint extents, k=2..7 (max total = 384+128+48+24+12+4 = 600)
    const long long OFD[8] = {0, OF_D1, OF_D2, OF_D3, OF_D4, OF_D5, OF_D6, OF_D7};
    int oyk[8], hyk[8], basek[8];
    int acc = 0;
#pragma unroll
    for (int k = 2; k <= 7; k++) {
        int n = 256 >> k;
        float sc = (float)(n - 1) / 255.f;
        int oy = (int)floorf(Y0 * sc);
        int ey = (int)floorf((Y0 + 15) * sc) + 1;
        if (ey > n - 1) ey = n - 1;
        oyk[k] = oy; hyk[k] = ey - oy + 1; basek[k] = acc;
        acc += hyk[k] * n;
    }
    for (int s = 0; s < 2; s++) {
#pragma unroll
        for (int k = 2; k <= 7; k++) {
            int n = 256 >> k;
            const float* srcp = ws + OFD[k] + (long long)(s * 512 + p) * n * n + oyk[k] * n;
            float* dstp = fpb + s * 600 + basek[k];
            int tot = hyk[k] * n;
            for (int i = tid; i < tot; i += 256) dstp[i] = srcp[i];
        }
    }

    // level-1 ring: rows cy1 (slot 0) and min(cy1+1,127) (slot 1)
    const float sc1 = 127.f / 255.f;
    const float* gP1 = ws + OF_D1 + (long long)p * 16384;
    const float* gN1 = gP1 + 512LL * 16384;
    int cy1 = (int)floorf(Y0 * sc1);
    {
        int i1 = min(cy1 + 1, 127);
        int c = tid & 127;
        if (tid < 128) {
            fp1P[0 * 128 + c] = gP1[cy1 * 128 + c];
            fp1P[1 * 128 + c] = gP1[i1 * 128 + c];
        } else {
            fp1N[0 * 128 + c] = gN1[cy1 * 128 + c];
            fp1N[1 * 128 + c] = gN1[i1 * 128 + c];
        }
    }
    __syncthreads();

    // per-thread per-level x-lerp constants
    int j0[8], j1[8]; float fxk[8];
#pragma unroll
    for (int k = 2; k <= 7; k++) {
        int n = 256 >> k;
        float sc = (float)(n - 1) / 255.f;
        float ux = tid * sc;
        int a = (int)ux; if (a > n - 1) a = n - 1;
        j0[k] = a; j1[k] = min(a + 1, n - 1);
        fxk[k] = ux - (float)a;
    }
    int j0_1, j1_1; float fx1;
    {
        float ux = tid * sc1;
        int a = (int)ux; if (a > 127) a = 127;
        j0_1 = a; j1_1 = min(a + 1, 127);
        fx1 = ux - (float)a;
    }

    // register cache: x-lerped footprint rows iy0 (xl0) and iy1 (xl1)
    float xl0P[8], xl1P[8], xl0N[8], xl1N[8];
    int cy[8];
#pragma unroll
    for (int k = 2; k <= 7; k++) {
        int n = 256 >> k;
        int i0 = oyk[k];
        int i1 = min(i0 + 1, n - 1);
        cy[k] = i0;
        int r1o = (i1 - oyk[k]) * n;
        float aP = fpb[basek[k] + j0[k]],        bP = fpb[basek[k] + j1[k]];
        float cP = fpb[basek[k] + r1o + j0[k]],  dP = fpb[basek[k] + r1o + j1[k]];
        xl0P[k] = aP + fxk[k] * (bP - aP);
        xl1P[k] = cP + fxk[k] * (dP - cP);
        float aN = fpb[600 + basek[k] + j0[k]],       bN = fpb[600 + basek[k] + j1[k]];
        float cN = fpb[600 + basek[k] + r1o + j0[k]], dN = fpb[600 + basek[k] + r1o + j1[k]];
        xl0N[k] = aN + fxk[k] * (bN - aN);
        xl1N[k] = cN + fxk[k] * (dN - cN);
    }
    float xl0P1, xl1P1, xl0N1, xl1N1;
    int cur1 = 1;   // slot holding the xl1 row
    {
        float a = fp1P[0 * 128 + j0_1], e = fp1P[0 * 128 + j1_1];
        float c = fp1P[1 * 128 + j0_1], d = fp1P[1 * 128 + j1_1];
        xl0P1 = a + fx1 * (e - a);
        xl1P1 = c + fx1 * (d - c);
        float an = fp1N[0 * 128 + j0_1], en = fp1N[0 * 128 + j1_1];
        float cn = fp1N[1 * 128 + j0_1], dn = fp1N[1 * 128 + j1_1];
        xl0N1 = an + fx1 * (en - an);
        xl1N1 = cn + fx1 * (dn - cn);
    }

    // level-0 streaming rings (rows lr-1, lr, lr+1)
    float hx0, hx1, hx2, hn0, hn1, hn2, cc1, cc2;
    {
        int b0 = 0 * 258 + tid;
        float a = cf[b0], b = cf[b0 + 1], c = cf[b0 + 2];
        hx0 = fmaxf(fmaxf(a, b), c); hn0 = fminf(fminf(a, b), c);
        int b1 = 1 * 258 + tid;
        float d = cf[b1], e = cf[b1 + 1], f = cf[b1 + 2];
        hx1 = fmaxf(fmaxf(d, e), f); hn1 = fminf(fminf(d, e), f);
        cc1 = e;
    }

    float* radp = rad + (long long)p * PLANE + (long long)Y0 * 256 + tid;

    for (int q = 0; q < 16; q++) {
        // next field row (lr+1 = q+2)
        int bn = (q + 2) * 258 + tid;
        float a = cf[bn], b = cf[bn + 1], c = cf[bn + 2];
        hx2 = fmaxf(fmaxf(a, b), c); hn2 = fminf(fminf(a, b), c);
        cc2 = b;

        float poolmax = fmaxf(fmaxf(hx0, hx1), hx2);
        float poolmin = fminf(fminf(hn0, hn1), hn2);
        float mP = fmaxf(fmaxf(cc1, 0.f), 0.99f * fmaxf(poolmax, 0.f));
        float mN = fmaxf(fmaxf(-cc1, 0.f), 0.99f * fmaxf(-poolmin, 0.f));

        int row = Y0 + q;

        // ---- level 1 (LDS ring; advance is block-uniform) ----
        {
            float uy = row * sc1;
            int i0 = (int)uy;
            if (i0 != cy1) {             // uniform across the whole block
                cy1 = i0;
                xl0P1 = xl1P1; xl0N1 = xl1N1;
                int i1n = min(i0 + 1, 127);
                int slot = cur1 ^ 1;
                __syncthreads();         // nobody still reads 'slot'
                int cc = tid & 127;
                if (tid < 128) fp1P[slot * 128 + cc] = gP1[i1n * 128 + cc];
                else           fp1N[slot * 128 + cc] = gN1[i1n * 128 + cc];
                __syncthreads();         // row loaded
                float aa = fp1P[slot * 128 + j0_1], ee = fp1P[slot * 128 + j1_1];
                xl1P1 = aa + fx1 * (ee - aa);
                float an = fp1N[slot * 128 + j0_1], en = fp1N[slot * 128 + j1_1];
                xl1N1 = an + fx1 * (en - an);
                cur1 = slot;
            }
            float fy = uy - (float)i0;
            mP = fmaxf(mP, xl0P1 + fy * (xl1P1 - xl0P1));
            mN = fmaxf(mN, xl0N1 + fy * (xl1N1 - xl0N1));
        }

        // ---- levels 2..7 (fully staged) ----
#pragma unroll
        for (int k = 2; k <= 7; k++) {
            int n = 256 >> k;
            float sc = (float)(n - 1) / 255.f;
            float uy = row * sc;
            int i0 = (int)uy;
            if (i0 != cy[k]) {           // wave-uniform advance (by exactly 1)
                cy[k] = i0;
                xl0P[k] = xl1P[k]; xl0N[k] = xl1N[k];
                int i1 = min(i0 + 1, n - 1);
                int ro = (i1 - oyk[k]) * n;
                float aP = fpb[basek[k] + ro + j0[k]], bP = fpb[basek[k] + ro + j1[k]];
                xl1P[k] = aP + fxk[k] * (bP - aP);
                float aN = fpb[600 + basek[k] + ro + j0[k]], bN = fpb[600 + basek[k] + ro + j1[k]];
                xl1N[k] = aN + fxk[k] * (bN - aN);
            }
            float fy = uy - (float)i0;
            mP = fmaxf(mP, xl0P[k] + fy * (xl1P[k] - xl0P[k]));
            mN = fmaxf(mN, xl0N[k] + fy * (xl1N[k] - xl0N[k]));
        }
        radp[q * 256] = mP - mN;

        hx0 = hx1; hx1 = hx2;
        hn0 = hn1; hn1 = hn2;
        cc1 = cc2;
    }
}

// ------------------------------------------------------------------ mlp ----
// io holds rad on entry, final output on exit (per-thread read set == write
// set; all reads precede all writes within a thread).
__global__ __launch_bounds__(256) void mlp_kernel(const float* __restrict__ x,
                                                  const float* __restrict__ w1,
                                                  const float* __restrict__ b1,
                                                  const float* __restrict__ w2,
                                                  const float* __restrict__ b2,
                                                  float* io) {
    const int y = blockIdx.x;   // 0..255
    const int b = blockIdx.y;   // 0..3
    const int col = threadIdx.x;

    float h[16];
#pragma unroll
    for (int o = 0; o < 16; o++) h[o] = b1[o];
    for (int c = 0; c < 128; c++) {
        float r = io[(long long)(b * 128 + c) * PLANE + y * 256 + col];
#pragma unroll
        for (int o = 0; o < 16; o++) h[o] += w1[o * 128 + c] * r;
    }
#pragma unroll
    for (int o = 0; o < 16; o++) h[o] = fmaxf(h[o], 0.f);
    for (int c = 0; c < 128; c++) {
        float z = b2[c];
#pragma unroll
        for (int o = 0; o < 16; o++) z += w2[c * 16 + o] * h[o];
        float mod = 1.f / (1.f + __expf(-z));
        long long idx = (long long)(b * 128 + c) * PLANE + y * 256 + col;
        io[idx] = x[idx] * mod;
    }
}

// -------------------------------------------------------------- launcher ----
extern "C" void kernel_launch(void* const* d_in, const int* in_sizes, int n_in,
                              void* d_out, int out_size, void* d_ws, size_t ws_size,
                              hipStream_t stream) {
    (void)in_sizes; (void)n_in; (void)out_size; (void)ws_size;
    const float* x  = (const float*)d_in[0];
    const float* w1 = (const float*)d_in[1];
    const float* b1 = (const float*)d_in[2];
    const float* w2 = (const float*)d_in[3];
    const float* b2 = (const float*)d_in[4];
    float* out = (float*)d_out;
    float* ws = (float*)d_ws;

    statsA_kernel<<<dim3(16, 512), 256, 0, stream>>>(x, ws);
    statsB_kernel<<<2, 256, 0, stream>>>(ws);
    field_kernel<<<dim3(16, 512), 256, 0, stream>>>(x, ws);
    pyramid_kernel<<<1024, 256, 0, stream>>>(ws);
    radiance_kernel<<<dim3(16, 512), 256, 0, stream>>>(x, ws, out);
    mlp_kernel<<<dim3(256, 4), 256, 0, stream>>>(x, w1, b1, w2, b2, out);
}

// Round 5
// 900.103 us; speedup vs baseline: 1.2122x; 1.0487x over previous
//
#include <hip/hip_runtime.h>
#include <cmath>

constexpr int BN = 4, CN = 128, HN = 256, WN = 256;
constexpr int NPLANE = BN * CN;          // 512
constexpr int PLANE  = HN * WN;          // 65536

// workspace layout (float offsets); end = 39,146,496 floats = 157 MB
constexpr long long OF_THR = 0;                                  // 1024
constexpr long long OF_R1  = 1024;                               // 2*512*128*128
constexpr long long OF_D1  = OF_R1 + 2LL * NPLANE * 128 * 128;
constexpr long long OF_D2  = OF_D1 + 2LL * NPLANE * 128 * 128;
constexpr long long OF_D3  = OF_D2 + 2LL * NPLANE * 64 * 64;
constexpr long long OF_D4  = OF_D3 + 2LL * NPLANE * 32 * 32;
constexpr long long OF_D5  = OF_D4 + 2LL * NPLANE * 16 * 16;
constexpr long long OF_D6  = OF_D5 + 2LL * NPLANE * 8 * 8;
constexpr long long OF_D7  = OF_D6 + 2LL * NPLANE * 4 * 4;
// stats partials are parked in the (not yet written) D1 region.

static __device__ __forceinline__ float sigm100(float a, float thr) {
    return 1.f / (1.f + __expf(-100.f * (a - thr))) + 1e-6f;
}

// --------------------------------------------------------------- statsA ----
// partial sums per (plane, 16-row strip) -> float4 partials in D1 region
__global__ __launch_bounds__(256) void statsA_kernel(const float* __restrict__ x,
                                                     float* __restrict__ ws) {
    const int strip = blockIdx.x;   // 0..15
    const int p = blockIdx.y;       // 0..511
    const int tid = threadIdx.x;
    const float* xp = x + (long long)p * PLANE + strip * 4096;
    float sp = 0, spp = 0, sn = 0, snn = 0;
    for (int i = tid; i < 4096; i += 256) {
        float v = xp[i];
        float a = fmaxf(v, 0.f), b = fmaxf(-v, 0.f);
        sp += a; spp += a * a;
        sn += b; snn += b * b;
    }
    __shared__ float red[256];
    float vals[4] = {sp, spp, sn, snn};
    float* dst = ws + OF_D1 + ((long long)p * 16 + strip) * 4;
    for (int q = 0; q < 4; q++) {
        red[tid] = vals[q];
        __syncthreads();
        for (int s = 128; s > 0; s >>= 1) {
            if (tid < s) red[tid] += red[tid + s];
            __syncthreads();
        }
        if (tid == 0) dst[q] = red[0];
        __syncthreads();
    }
}

// --------------------------------------------------------------- statsB ----
__global__ __launch_bounds__(256) void statsB_kernel(float* __restrict__ ws) {
    int p = blockIdx.x * 256 + threadIdx.x;   // grid 2 x 256 -> 512 planes
    if (p >= 512) return;
    double sp = 0, spp = 0, sn = 0, snn = 0;
    for (int s = 0; s < 16; s++) {
        const float* src = ws + OF_D1 + ((long long)p * 16 + s) * 4;
        sp += src[0]; spp += src[1]; sn += src[2]; snn += src[3];
    }
    double N = (double)PLANE;
    double meanP = sp / N, meanN = sn / N;
    double varP = (spp - sp * sp / N) / (N - 1.0);
    double varN = (snn - sn * sn / N) / (N - 1.0);
    varP = varP > 0 ? varP : 0;
    varN = varN > 0 ? varN : 0;
    ws[OF_THR + p]       = (float)(meanP + 2.0 * sqrt(varP));
    ws[OF_THR + 512 + p] = (float)(meanN + 2.0 * sqrt(varN));
}

// -------------------------------------------------- field -> r1 only ----
// Combined-sign field c = v * sigm(|v|, thr_sign). One block = one 64x64
// tile. The 4 pooled values each resize output needs are computed directly
// from cf with the same 9-point windows / clamps / lerp (bit-identical).
// LDS 17.4 KB => 8 blocks/CU.
#define POOL9(LY, LX, MX, MN)                                                 \
    {   const float* q_ = cf + (LY) * 66 + (LX);                              \
        float t0 = q_[0],   t1 = q_[1],   t2 = q_[2];                         \
        float u0 = q_[66],  u1 = q_[67],  u2 = q_[68];                        \
        float w0 = q_[132], w1 = q_[133], w2 = q_[134];                       \
        MX = fmaxf(fmaxf(fmaxf(t0, t1), t2),                                  \
             fmaxf(fmaxf(fmaxf(u0, u1), u2),                                  \
                   fmaxf(fmaxf(w0, w1), w2)));                                \
        MN = fminf(fminf(fminf(t0, t1), t2),                                  \
             fminf(fminf(fminf(u0, u1), u2),                                  \
                   fminf(fminf(w0, w1), w2))); }

__global__ __launch_bounds__(256, 8) void field_kernel(const float* __restrict__ x,
                                                       float* __restrict__ ws) {
    const int tile = blockIdx.x;           // 0..15  (ty*4+tx)
    const int p = blockIdx.y;              // 0..511
    const int ty = tile >> 2, tx = tile & 3;
    const int y0 = ty * 64, x0 = tx * 64;
    const int tid = threadIdx.x;

    __shared__ float cf[66 * 66];

    const float thrP = ws[OF_THR + p];
    const float thrN = ws[OF_THR + 512 + p];
    const float* xp = x + (long long)p * PLANE;

    for (int i = tid; i < 66 * 66; i += 256) {
        int ly = i / 66, lx = i - ly * 66;
        int gy = min(max(y0 - 1 + ly, 0), 255);
        int gx = min(max(x0 - 1 + lx, 0), 255);
        float v = xp[gy * 256 + gx];
        float thr = v > 0.f ? thrP : thrN;
        cf[i] = v * sigm100(fabsf(v), thr);
    }
    __syncthreads();

    const float g1 = 0.99f;
    const float S = (float)(255.0 / 127.0);
    for (int i = tid; i < 32 * 32; i += 256) {
        int ry = i >> 5, rx = i & 31;
        int jy = ty * 32 + ry, jx = tx * 32 + rx;
        float uy = jy * S, ux = jx * S;
        int iy0 = (int)floorf(uy), ix0 = (int)floorf(ux);
        int iy1 = min(iy0 + 1, 255), ix1 = min(ix0 + 1, 255);
        float fy = uy - iy0, fx = ux - ix0;
        int ly0 = min(max(iy0 - y0, 0), 63), ly1 = min(max(iy1 - y0, 0), 63);
        int lx0 = min(max(ix0 - x0, 0), 63), lx1 = min(max(ix1 - x0, 0), 63);

        float amx, amn, bmx, bmn, cmx, cmn, dmx, dmn;
        POOL9(ly0, lx0, amx, amn)
        POOL9(ly0, lx1, bmx, bmn)
        POOL9(ly1, lx0, cmx, cmn)
        POOL9(ly1, lx1, dmx, dmn)

        float aP = fmaxf(amx, 0.f) * g1, bP = fmaxf(bmx, 0.f) * g1;
        float cP = fmaxf(cmx, 0.f) * g1, dP = fmaxf(dmx, 0.f) * g1;
        float vP = (aP * (1.f - fy) + cP * fy) * (1.f - fx) + (bP * (1.f - fy) + dP * fy) * fx;
        float aN = fmaxf(-amn, 0.f) * g1, bN = fmaxf(-bmn, 0.f) * g1;
        float cN = fmaxf(-cmn, 0.f) * g1, dN = fmaxf(-dmn, 0.f) * g1;
        float vN = (aN * (1.f - fy) + cN * fy) * (1.f - fx) + (bN * (1.f - fy) + dN * fy) * fx;
        ws[OF_R1 + (long long)p * 16384 + jy * 128 + jx] = vP;
        ws[OF_R1 + (long long)(512 + p) * 16384 + jy * 128 + jx] = vN;
    }
}

// -------------------------------------------------------------- pyramid ----
// pool1 + 6 pstep launches fused. One block per sign-plane (1024 blocks).
// D1 computed from global R1 (pool3 * 0.99^2), written to global AND kept
// in LDS; levels 2..7 ping-pong A<->B in LDS, each also written to global
// for radiance. Math identical to the old pool1/pstep kernels; gammas by
// double repeated squaring (== std::pow to the ulp for these arguments).
__global__ __launch_bounds__(256, 2) void pyramid_kernel(float* __restrict__ ws) {
    const int ps = blockIdx.x;        // 0..1023 (sign*512 + plane)
    const int tid = threadIdx.x;
    __shared__ float A[16384];        // 64 KB
    __shared__ float B[4096];         // 16 KB

    // ---- level 1: 3x3 max pool on R1, * 0.99^2 ----
    const float* src = ws + OF_R1 + (long long)ps * 16384;
    float* d1 = ws + OF_D1 + (long long)ps * 16384;
    double gd = 0.99 * 0.99;
    {
        float g2 = (float)gd;
        for (int i = tid; i < 16384; i += 256) {
            int oy = i >> 7, ox = i & 127;
            float m = -INFINITY;
            for (int dy = -1; dy <= 1; dy++) {
                int yy = oy + dy;
                if (yy < 0 || yy > 127) continue;
                for (int dx = -1; dx <= 1; dx++) {
                    int xx = ox + dx;
                    if (xx < 0 || xx > 127) continue;
                    m = fmaxf(m, src[yy * 128 + xx]);
                }
            }
            float v = m * g2;
            d1[i] = v; A[i] = v;
        }
    }
    __syncthreads();

    // ---- levels 2..7: bilinear-downscale + pool3, ping-pong in LDS ----
    const long long OFD[8] = {0, OF_D1, OF_D2, OF_D3, OF_D4, OF_D5, OF_D6, OF_D7};
    float* curL = A;
    float* nxtL = B;
#pragma unroll
    for (int k = 2; k <= 7; k++) {
        const int m = 256 >> (k - 1), n = 256 >> k;
        const int logn = 8 - k;
        gd = gd * gd;                                   // 0.99^(2^k)
        const float gamma = (float)gd;
        const float scale = (float)((double)(m - 1) / (double)(n - 1));
        float* dst = ws + OFD[k] + (long long)ps * n * n;
        for (int i = tid; i < n * n; i += 256) {
            int oy = i >> logn, ox = i & (n - 1);
            float best = -INFINITY;
            for (int dy = -1; dy <= 1; dy++) {
                int yy = oy + dy;
                if (yy < 0 || yy >= n) continue;
                float uy = yy * scale;
                int iy0 = (int)floorf(uy);
                if (iy0 > m - 1) iy0 = m - 1;
                int iy1 = min(iy0 + 1, m - 1);
                float fy = uy - iy0;
                for (int dx = -1; dx <= 1; dx++) {
                    int xx = ox + dx;
                    if (xx < 0 || xx >= n) continue;
                    float ux = xx * scale;
                    int ix0 = (int)floorf(ux);
                    if (ix0 > m - 1) ix0 = m - 1;
                    int ix1 = min(ix0 + 1, m - 1);
                    float fx = ux - ix0;
                    float a = curL[iy0 * m + ix0], b = curL[iy0 * m + ix1];
                    float c = curL[iy1 * m + ix0], d = curL[iy1 * m + ix1];
                    float v = (a * (1.f - fy) + c * fy) * (1.f - fx) + (b * (1.f - fy) + d * fy) * fx;
                    best = fmaxf(best, v);
                }
            }
            float o = best * gamma;
            dst[i] = o; nxtL[i] = o;
        }
        __syncthreads();
        float* t = curL; curL = nxtL; nxtL = t;
    }
}

// ------------------------------------------------------------- radiance ----
// Round-4 structure (LDS-staged cf + fpb k=2..7 + level-1 2-row LDS ring,
// 25.6 KB). ROUND-4 LESSON: __launch_bounds__ min-waves >= 6 makes the
// backend's occupancy-targeted scheduler insert scratch spills for this
// kernel (WRITE_SIZE +221 MB exactly, VGPR reported 40) even though final
// usage fits the cap. min-waves=4 is the proven no-spill config (round 0:
// 52 VGPR, WRITE exactly 131072 KB) and does NOT limit runtime occupancy
// upward: with ~52 VGPR the occupancy is LDS-limited at 160/25.6 = 6
// blocks/CU (75%), which is the occupancy gain we wanted all along.
__global__ __launch_bounds__(256, 4) void radiance_kernel(const float* __restrict__ x,
                                                          const float* __restrict__ ws,
                                                          float* __restrict__ rad) {
    const int tY = blockIdx.x;     // 0..15
    const int p = blockIdx.y;      // 0..511
    const int Y0 = tY * 16;
    const int tid = threadIdx.x;   // = column

    __shared__ float cf[18 * 258];   // combined field rows Y0-1..Y0+16 (18576 B)
    __shared__ float fpb[2 * 600];   // pyramid footprints k=2..7, both signs (4800 B)
    __shared__ float fp1P[2 * 128];  // level-1 ring, sign P (1024 B)
    __shared__ float fp1N[2 * 128];  // level-1 ring, sign N (1024 B)

    const float thrP = ws[OF_THR + p];
    const float thrN = ws[OF_THR + 512 + p];
    const float* xp = x + (long long)p * PLANE;

    // stage combined field; cols duplicated at 0 and 257 (clamp trick)
    for (int r = 0; r < 18; r++) {
        int gy = min(max(Y0 - 1 + r, 0), 255);
        float v = xp[gy * 256 + tid];
        float thr = v > 0.f ? thrP : thrN;
        float c = v * sigm100(fabsf(v), thr);
        cf[r * 258 + tid + 1] = c;
        if (tid == 0) cf[r * 258] = c;
        if (tid == 255) cf[r * 258 + 257] = c;
    }

    // footprint extents, k=2..7 (max total = 384+128+48+24+12+4 = 600)
    const long long OFD[8] = {0, OF_D1, OF_D2, OF_D3, OF_D4, OF_D5, OF_D6, OF_D7};
    int oyk[8], hyk[8], basek[8];
    int acc = 0;
#pragma unroll
    for (int k = 2; k <= 7; k++) {
        int n = 256 >> k;
        float sc = (float)(n - 1) / 255.f;
        int oy = (int)floorf(Y0 * sc);
        int ey = (int)floorf((Y0 + 15) * sc) + 1;
        if (ey > n - 1) ey = n - 1;
        oyk[k] = oy; hyk[k] = ey - oy + 1; basek[k] = acc;
        acc += hyk[k] * n;
    }
    for (int s = 0; s < 2; s++) {
#pragma unroll
        for (int k = 2; k <= 7; k++) {
            int n = 256 >> k;
            const float* srcp = ws + OFD[k] + (long long)(s * 512 + p) * n * n + oyk[k] * n;
            float* dstp = fpb + s * 600 + basek[k];
            int tot = hyk[k] * n;
            for (int i = tid; i < tot; i += 256) dstp[i] = srcp[i];
        }
    }

    // level-1 ring: rows cy1 (slot 0) and min(cy1+1,127) (slot 1)
    const float sc1 = 127.f / 255.f;
    const float* gP1 = ws + OF_D1 + (long long)p * 16384;
    const float* gN1 = gP1 + 512LL * 16384;
    int cy1 = (int)floorf(Y0 * sc1);
    {
        int i1 = min(cy1 + 1, 127);
        int c = tid & 127;
        if (tid < 128) {
            fp1P[0 * 128 + c] = gP1[cy1 * 128 + c];
            fp1P[1 * 128 + c] = gP1[i1 * 128 + c];
        } else {
            fp1N[0 * 128 + c] = gN1[cy1 * 128 + c];
            fp1N[1 * 128 + c] = gN1[i1 * 128 + c];
        }
    }
    __syncthreads();

    // per-thread per-level x-lerp constants
    int j0[8], j1[8]; float fxk[8];
#pragma unroll
    for (int k = 2; k <= 7; k++) {
        int n = 256 >> k;
        float sc = (float)(n - 1) / 255.f;
        float ux = tid * sc;
        int a = (int)ux; if (a > n - 1) a = n - 1;
        j0[k] = a; j1[k] = min(a + 1, n - 1);
        fxk[k] = ux - (float)a;
    }
    int j0_1, j1_1; float fx1;
    {
        float ux = tid * sc1;
        int a = (int)ux; if (a > 127) a = 127;
        j0_1 = a; j1_1 = min(a + 1, 127);
        fx1 = ux - (float)a;
    }

    // register cache: x-lerped footprint rows iy0 (xl0) and iy1 (xl1)
    float xl0P[8], xl1P[8], xl0N[8], xl1N[8];
    int cy[8];
#pragma unroll
    for (int k = 2; k <= 7; k++) {
        int n = 256 >> k;
        int i0 = oyk[k];
        int i1 = min(i0 + 1, n - 1);
        cy[k] = i0;
        int r1o = (i1 - oyk[k]) * n;
        float aP = fpb[basek[k] + j0[k]],        bP = fpb[basek[k] + j1[k]];
        float cP = fpb[basek[k] + r1o + j0[k]],  dP = fpb[basek[k] + r1o + j1[k]];
        xl0P[k] = aP + fxk[k] * (bP - aP);
        xl1P[k] = cP + fxk[k] * (dP - cP);
        float aN = fpb[600 + basek[k] + j0[k]],       bN = fpb[600 + basek[k] + j1[k]];
        float cN = fpb[600 + basek[k] + r1o + j0[k]], dN = fpb[600 + basek[k] + r1o + j1[k]];
        xl0N[k] = aN + fxk[k] * (bN - aN);
        xl1N[k] = cN + fxk[k] * (dN - cN);
    }
    float xl0P1, xl1P1, xl0N1, xl1N1;
    int cur1 = 1;   // slot holding the xl1 row
    {
        float a = fp1P[0 * 128 + j0_1], e = fp1P[0 * 128 + j1_1];
        float c = fp1P[1 * 128 + j0_1], d = fp1P[1 * 128 + j1_1];
        xl0P1 = a + fx1 * (e - a);
        xl1P1 = c + fx1 * (d - c);
        float an = fp1N[0 * 128 + j0_1], en = fp1N[0 * 128 + j1_1];
        float cn = fp1N[1 * 128 + j0_1], dn = fp1N[1 * 128 + j1_1];
        xl0N1 = an + fx1 * (en - an);
        xl1N1 = cn + fx1 * (dn - cn);
    }

    // level-0 streaming rings (rows lr-1, lr, lr+1)
    float hx0, hx1, hx2, hn0, hn1, hn2, cc1, cc2;
    {
        int b0 = 0 * 258 + tid;
        float a = cf[b0], b = cf[b0 + 1], c = cf[b0 + 2];
        hx0 = fmaxf(fmaxf(a, b), c); hn0 = fminf(fminf(a, b), c);
        int b1 = 1 * 258 + tid;
        float d = cf[b1], e = cf[b1 + 1], f = cf[b1 + 2];
        hx1 = fmaxf(fmaxf(d, e), f); hn1 = fminf(fminf(d, e), f);
        cc1 = e;
    }

    float* radp = rad + (long long)p * PLANE + (long long)Y0 * 256 + tid;

    for (int q = 0; q < 16; q++) {
        // next field row (lr+1 = q+2)
        int bn = (q + 2) * 258 + tid;
        float a = cf[bn], b = cf[bn + 1], c = cf[bn + 2];
        hx2 = fmaxf(fmaxf(a, b), c); hn2 = fminf(fminf(a, b), c);
        cc2 = b;

        float poolmax = fmaxf(fmaxf(hx0, hx1), hx2);
        float poolmin = fminf(fminf(hn0, hn1), hn2);
        float mP = fmaxf(fmaxf(cc1, 0.f), 0.99f * fmaxf(poolmax, 0.f));
        float mN = fmaxf(fmaxf(-cc1, 0.f), 0.99f * fmaxf(-poolmin, 0.f));

        int row = Y0 + q;

        // ---- level 1 (LDS ring; advance is block-uniform) ----
        {
            float uy = row * sc1;
            int i0 = (int)uy;
            if (i0 != cy1) {             // uniform across the whole block
                cy1 = i0;
                xl0P1 = xl1P1; xl0N1 = xl1N1;
                int i1n = min(i0 + 1, 127);
                int slot = cur1 ^ 1;
                __syncthreads();         // nobody still reads 'slot'
                int cc = tid & 127;
                if (tid < 128) fp1P[slot * 128 + cc] = gP1[i1n * 128 + cc];
                else           fp1N[slot * 128 + cc] = gN1[i1n * 128 + cc];
                __syncthreads();         // row loaded
                float aa = fp1P[slot * 128 + j0_1], ee = fp1P[slot * 128 + j1_1];
                xl1P1 = aa + fx1 * (ee - aa);
                float an = fp1N[slot * 128 + j0_1], en = fp1N[slot * 128 + j1_1];
                xl1N1 = an + fx1 * (en - an);
                cur1 = slot;
            }
            float fy = uy - (float)i0;
            mP = fmaxf(mP, xl0P1 + fy * (xl1P1 - xl0P1));
            mN = fmaxf(mN, xl0N1 + fy * (xl1N1 - xl0N1));
        }

        // ---- levels 2..7 (fully staged) ----
#pragma unroll
        for (int k = 2; k <= 7; k++) {
            int n = 256 >> k;
            float sc = (float)(n - 1) / 255.f;
            float uy = row * sc;
            int i0 = (int)uy;
            if (i0 != cy[k]) {           // wave-uniform advance (by exactly 1)
                cy[k] = i0;
                xl0P[k] = xl1P[k]; xl0N[k] = xl1N[k];
                int i1 = min(i0 + 1, n - 1);
                int ro = (i1 - oyk[k]) * n;
                float aP = fpb[basek[k] + ro + j0[k]], bP = fpb[basek[k] + ro + j1[k]];
                xl1P[k] = aP + fxk[k] * (bP - aP);
                float aN = fpb[600 + basek[k] + ro + j0[k]], bN = fpb[600 + basek[k] + ro + j1[k]];
                xl1N[k] = aN + fxk[k] * (bN - aN);
            }
            float fy = uy - (float)i0;
            mP = fmaxf(mP, xl0P[k] + fy * (xl1P[k] - xl0P[k]));
            mN = fmaxf(mN, xl0N[k] + fy * (xl1N[k] - xl0N[k]));
        }
        radp[q * 256] = mP - mN;

        hx0 = hx1; hx1 = hx2;
        hn0 = hn1; hn1 = hn2;
        cc1 = cc2;
    }
}

// ------------------------------------------------------------------ mlp ----
// io holds rad on entry, final output on exit (per-thread read set == write
// set; all reads precede all writes within a thread).
__global__ __launch_bounds__(256) void mlp_kernel(const float* __restrict__ x,
                                                  const float* __restrict__ w1,
                                                  const float* __restrict__ b1,
                                                  const float* __restrict__ w2,
                                                  const float* __restrict__ b2,
                                                  float* io) {
    const int y = blockIdx.x;   // 0..255
    const int b = blockIdx.y;   // 0..3
    const int col = threadIdx.x;

    float h[16];
#pragma unroll
    for (int o = 0; o < 16; o++) h[o] = b1[o];
    for (int c = 0; c < 128; c++) {
        float r = io[(long long)(b * 128 + c) * PLANE + y * 256 + col];
#pragma unroll
        for (int o = 0; o < 16; o++) h[o] += w1[o * 128 + c] * r;
    }
#pragma unroll
    for (int o = 0; o < 16; o++) h[o] = fmaxf(h[o], 0.f);
    for (int c = 0; c < 128; c++) {
        float z = b2[c];
#pragma unroll
        for (int o = 0; o < 16; o++) z += w2[c * 16 + o] * h[o];
        float mod = 1.f / (1.f + __expf(-z));
        long long idx = (long long)(b * 128 + c) * PLANE + y * 256 + col;
        io[idx] = x[idx] * mod;
    }
}

// -------------------------------------------------------------- launcher ----
extern "C" void kernel_launch(void* const* d_in, const int* in_sizes, int n_in,
                              void* d_out, int out_size, void* d_ws, size_t ws_size,
                              hipStream_t stream) {
    (void)in_sizes; (void)n_in; (void)out_size; (void)ws_size;
    const float* x  = (const float*)d_in[0];
    const float* w1 = (const float*)d_in[1];
    const float* b1 = (const float*)d_in[2];
    const float* w2 = (const float*)d_in[3];
    const float* b2 = (const float*)d_in[4];
    float* out = (float*)d_out;
    float* ws = (float*)d_ws;

    statsA_kernel<<<dim3(16, 512), 256, 0, stream>>>(x, ws);
    statsB_kernel<<<2, 256, 0, stream>>>(ws);
    field_kernel<<<dim3(16, 512), 256, 0, stream>>>(x, ws);
    pyramid_kernel<<<1024, 256, 0, stream>>>(ws);
    radiance_kernel<<<dim3(16, 512), 256, 0, stream>>>(x, ws, out);
    mlp_kernel<<<dim3(256, 4), 256, 0, stream>>>(x, w1, b1, w2, b2, out);
}